// Round 10
// baseline (906.945 us; speedup 1.0000x reference)
//
#include <hip/hip_runtime.h>

#define N_NODES 50000
#define N_EDGES 800000
#define N_GRAPHS 512
#define HIDDEN 256
#define NODE_FEAT 9
#define LAYERS 4
#define BUCKET 64   // max degree capacity (mean 16, max ~35 for uniform random)
#define SLICES 8    // column slices for XCD-local aggregation (32 cols = 64 B each)

typedef float floatx4 __attribute__((ext_vector_type(4)));
typedef short short8 __attribute__((ext_vector_type(8)));

__device__ __forceinline__ float bf2f(unsigned u) {
    unsigned v = u << 16;
    float f;
    __builtin_memcpy(&f, &v, 4);
    return f;
}
__device__ __forceinline__ unsigned short f2bf(float f) {
    unsigned v;
    __builtin_memcpy(&v, &f, 4);
    v += 0x7FFFu + ((v >> 16) & 1u);   // round-to-nearest-even
    return (unsigned short)(v >> 16);
}

// ---------------- one-pass bucketed CSR build ----------------
__global__ void fillb_kernel(const int* __restrict__ src, const int* __restrict__ dst,
                             int* __restrict__ cnt, int* __restrict__ col_src, int E) {
    int e = blockIdx.x * blockDim.x + threadIdx.x;
    if (e < E) {
        int d = dst[e];
        int pos = atomicAdd(&cnt[d], 1);
        if (pos < BUCKET) col_src[d * BUCKET + pos] = src[e];
    }
}

__global__ void dinv_kernel(const int* __restrict__ cnt, float* __restrict__ dinv, int N) {
    int i = blockIdx.x * blockDim.x + threadIdx.x;
    if (i < N) dinv[i] = rsqrtf((float)(cnt[i] + 1));   // +1 self loop
}

// ---------------- graph boundary search (batch is sorted) ----------------
__global__ void findstart_kernel(const int* __restrict__ batch, int* __restrict__ gstart) {
    int g = blockIdx.x * blockDim.x + threadIdx.x;
    if (g > N_GRAPHS) return;
    if (g == N_GRAPHS) { gstart[g] = N_NODES; return; }
    int lo = 0, hi = N_NODES;
    while (lo < hi) {
        int mid = (lo + hi) >> 1;
        if (batch[mid] < g) lo = mid + 1; else hi = mid;
    }
    gstart[g] = lo;
}

// ---------------- W pre-pack into MFMA B-fragment layout (bf16) ----------------
__global__ __launch_bounds__(256) void packW_kernel(const float* __restrict__ W,
                                                    unsigned short* __restrict__ Wsw) {
    int idx = blockIdx.x * 256 + threadIdx.x;   // 0..32767
    int lane = idx & 63;
    int ct   = (idx >> 6) & 15;
    int ks   = (idx >> 10) & 7;
    int l    = idx >> 13;
    int n = ct * 16 + (lane & 15);
    int kbase = ks * 32 + (lane >> 4) * 8;
    const float* Wl = W + (size_t)l * HIDDEN * HIDDEN;
    alignas(16) unsigned short tmp[8];
    #pragma unroll
    for (int j = 0; j < 8; j++)
        tmp[j] = f2bf(Wl[(size_t)(kbase + j) * HIDDEN + n]);
    *(uint4*)&Wsw[(size_t)idx * 8] = *(const uint4*)tmp;
}

// ---------------- embed: h = relu(x @ embW + embb), bf16 out ----------------
__global__ __launch_bounds__(256) void embed_kernel(const float* __restrict__ x,
                                                    const float* __restrict__ W,
                                                    const float* __restrict__ b,
                                                    unsigned short* __restrict__ h) {
    int n = blockIdx.x;
    int c = threadIdx.x;
    float acc = b[c];
    #pragma unroll
    for (int k = 0; k < NODE_FEAT; k++)
        acc += x[n * NODE_FEAT + k] * W[k * HIDDEN + c];
    h[(size_t)n * HIDDEN + c] = f2bf(fmaxf(acc, 0.0f));
}

// ---------------- hw = h @ W  (bf16 MFMA; depth-2 W prefetch) ----------------
__global__ __launch_bounds__(256, 2) void gemm_mfma(const unsigned short* __restrict__ hin,
                                                    const unsigned short* __restrict__ Wsw,
                                                    unsigned short* __restrict__ hwout, int N) {
    __shared__ unsigned short As[64][264];   // +8 pad; reused as C-buffer in epilogue
    int t = threadIdx.x;
    int wv = t >> 6, lane = t & 63, quad = lane >> 4, l15 = lane & 15;
    int n0 = blockIdx.x * 64;
    const uint4* h4 = (const uint4*)hin;     // 32 uint4 per row

    // A-tile staging loads
    uint4 av[8];
    #pragma unroll
    for (int i = 0; i < 8; i++) {
        int j = t + i * 256;
        int r = j >> 5;
        int c = j & 31;
        int n = n0 + r;
        av[i] = make_uint4(0u, 0u, 0u, 0u);
        if (n < N) av[i] = h4[(size_t)n * 32 + c];
    }
    // prime 2-deep W-fragment prefetch (rotating 3-buffer)
    const short8* Wl = (const short8*)Wsw;
    short8 bq[3][4];
    #pragma unroll
    for (int p = 0; p < 2; p++)
        #pragma unroll
        for (int ci = 0; ci < 4; ci++)
            bq[p][ci] = Wl[(size_t)(p * 16 + wv * 4 + ci) * 64 + lane];
    // LDS write of A tile
    #pragma unroll
    for (int i = 0; i < 8; i++) {
        int j = t + i * 256;
        int r = j >> 5;
        int c = j & 31;
        *(uint4*)&As[r][c * 8] = av[i];
    }
    __syncthreads();

    floatx4 acc[4][4];
    #pragma unroll
    for (int i = 0; i < 4; i++)
        #pragma unroll
        for (int j = 0; j < 4; j++)
            acc[i][j] = (floatx4){0.f, 0.f, 0.f, 0.f};

    #pragma unroll
    for (int ks = 0; ks < 8; ks++) {
        if (ks < 6) {
            #pragma unroll
            for (int ci = 0; ci < 4; ci++)
                bq[(ks + 2) % 3][ci] = Wl[(size_t)((ks + 2) * 16 + wv * 4 + ci) * 64 + lane];
        }
        short8 a[4];
        #pragma unroll
        for (int rt = 0; rt < 4; rt++)
            a[rt] = *(const short8*)&As[rt * 16 + l15][ks * 32 + quad * 8];
        #pragma unroll
        for (int rt = 0; rt < 4; rt++)
            #pragma unroll
            for (int ci = 0; ci < 4; ci++)
                acc[rt][ci] = __builtin_amdgcn_mfma_f32_16x16x32_bf16(a[rt], bq[ks % 3][ci], acc[rt][ci], 0, 0, 0);
    }

    // epilogue: transpose via LDS (reuse As), coalesced 16B stores
    __syncthreads();
    #pragma unroll
    for (int rt = 0; rt < 4; rt++) {
        #pragma unroll
        for (int ci = 0; ci < 4; ci++) {
            int col = (wv * 4 + ci) * 16 + l15;
            int rowb = rt * 16 + quad * 4;
            #pragma unroll
            for (int reg = 0; reg < 4; reg++)
                As[rowb + reg][col] = f2bf(acc[rt][ci][reg]);
        }
    }
    __syncthreads();
    #pragma unroll
    for (int i = 0; i < 8; i++) {
        int j = t + i * 256;
        int r = j >> 5;
        int c = j & 31;
        int n = n0 + r;
        if (n < N)
            *(uint4*)&hwout[(size_t)n * HIDDEN + c * 8] = *(const uint4*)&As[r][c * 8];
    }
}

// ---------------- XCD-local column-sliced aggregation ----------------
// slice = blockIdx % 8 -> pinned to one XCD under round-robin dispatch; that XCD's
// L2 holds the whole 3.2 MB column slice of hw. Row = 64 uint2 (512 B); a slice
// is 8 uint2 (64 B). 8-lane subgroups: sl picks the uint2, sub picks the node.
__global__ __launch_bounds__(256) void agg_slice(const unsigned short* __restrict__ hw,
                                                 const int* __restrict__ cnt,
                                                 const int* __restrict__ col_src,
                                                 const float* __restrict__ dinv,
                                                 const float* __restrict__ bias,
                                                 unsigned short* __restrict__ hout) {
    int slice = blockIdx.x & (SLICES - 1);
    int chunk = blockIdx.x / SLICES;
    int t = threadIdx.x;
    int wv = t >> 6, lane = t & 63;
    int sub = lane >> 3, sl = lane & 7;
    const uint2* hw2 = (const uint2*)hw;       // 64 uint2 per row
    int ci = slice * 8 + sl;                   // uint2 index within row (0..63)
    float4 bA = *(const float4*)&bias[slice * 32 + sl * 4];

    #pragma unroll
    for (int it = 0; it < 2; it++) {
        int n = chunk * 64 + it * 32 + wv * 8 + sub;
        if (n < N_NODES) {
            float dn = dinv[n];
            int deg = cnt[n]; if (deg > BUCKET) deg = BUCKET;
            uint2 su = hw2[(size_t)n * 64 + ci];
            float sc = dn * dn;
            float a0 = bf2f(su.x & 0xFFFFu) * sc + bA.x;
            float a1 = bf2f(su.x >> 16)     * sc + bA.y;
            float a2 = bf2f(su.y & 0xFFFFu) * sc + bA.z;
            float a3 = bf2f(su.y >> 16)     * sc + bA.w;
            const int* bucket = col_src + (size_t)n * BUCKET;
            for (int k = 0; k < deg; k++) {
                int s = bucket[k];
                float nr = dinv[s] * dn;
                uint2 u = hw2[(size_t)s * 64 + ci];
                a0 += nr * bf2f(u.x & 0xFFFFu);
                a1 += nr * bf2f(u.x >> 16);
                a2 += nr * bf2f(u.y & 0xFFFFu);
                a3 += nr * bf2f(u.y >> 16);
            }
            unsigned p0 = (unsigned)f2bf(fmaxf(a0, 0.f)) | ((unsigned)f2bf(fmaxf(a1, 0.f)) << 16);
            unsigned p1 = (unsigned)f2bf(fmaxf(a2, 0.f)) | ((unsigned)f2bf(fmaxf(a3, 0.f)) << 16);
            ((uint2*)hout)[(size_t)n * 64 + ci] = make_uint2(p0, p1);
        }
    }
}

// ---------------- pool + head, no atomics ----------------
__global__ __launch_bounds__(256) void pool2_kernel(const unsigned short* __restrict__ h,
                                                    const int* __restrict__ gstart,
                                                    const float* __restrict__ outW,
                                                    const float* __restrict__ outb,
                                                    float* __restrict__ out) {
    __shared__ float sred[4];
    int g = blockIdx.x;
    int t = threadIdx.x;
    int s = gstart[g], e = gstart[g + 1];
    int half = t >> 7;
    int tc = t & 127;
    float w0 = outW[2 * tc], w1 = outW[2 * tc + 1];
    float acc = 0.0f;
    for (int n = s + half; n < e; n += 2) {
        unsigned u = *(const unsigned*)&h[(size_t)n * HIDDEN + 2 * tc];
        acc += w0 * bf2f(u & 0xFFFFu) + w1 * bf2f(u >> 16);
    }
    #pragma unroll
    for (int off = 32; off > 0; off >>= 1) acc += __shfl_down(acc, off, 64);
    if ((t & 63) == 0) sred[t >> 6] = acc;
    __syncthreads();
    if (t == 0) {
        float tot = sred[0] + sred[1] + sred[2] + sred[3];
        float cntf = (float)(e - s);
        out[g] = tot / fmaxf(cntf, 1.0f) + outb[0];
    }
}

extern "C" void kernel_launch(void* const* d_in, const int* in_sizes, int n_in,
                              void* d_out, int out_size, void* d_ws, size_t ws_size,
                              hipStream_t stream) {
    const float* x     = (const float*)d_in[0];
    const int*   edge  = (const int*)d_in[1];
    const int*   src   = edge;
    const int*   dst   = edge + N_EDGES;
    const int*   batch = (const int*)d_in[2];
    const float* embW  = (const float*)d_in[3];
    const float* embb  = (const float*)d_in[4];
    const float* convW = (const float*)d_in[5];
    const float* convb = (const float*)d_in[6];
    const float* outW  = (const float*)d_in[7];
    const float* outb  = (const float*)d_in[8];
    float* out = (float*)d_out;

    char* ws = (char*)d_ws;
    size_t off = 0;
    auto take = [&](size_t bytes) { char* p = ws + off; off += (bytes + 255) & ~(size_t)255; return p; };
    int*   cnt     = (int*)  take((size_t)N_NODES * 4);
    int*   col_src = (int*)  take((size_t)N_NODES * BUCKET * 4);
    float* dinv    = (float*)take((size_t)N_NODES * 4);
    int*   gstart  = (int*)  take((size_t)(N_GRAPHS + 1) * 4);
    unsigned short* Wsw = (unsigned short*)take((size_t)LAYERS * 8 * 16 * 64 * 8 * 2);
    unsigned short* h0  = (unsigned short*)take((size_t)N_NODES * HIDDEN * 2);
    unsigned short* h1  = (unsigned short*)take((size_t)N_NODES * HIDDEN * 2);

    hipMemsetAsync(cnt, 0, (size_t)N_NODES * 4, stream);

    fillb_kernel<<<(N_EDGES + 255) / 256, 256, 0, stream>>>(src, dst, cnt, col_src, N_EDGES);
    dinv_kernel<<<(N_NODES + 255) / 256, 256, 0, stream>>>(cnt, dinv, N_NODES);
    findstart_kernel<<<3, 256, 0, stream>>>(batch, gstart);
    packW_kernel<<<128, 256, 0, stream>>>(convW, Wsw);
    embed_kernel<<<N_NODES, 256, 0, stream>>>(x, embW, embb, h0);

    int agg_grid = ((N_NODES + 63) / 64) * SLICES;   // 782 * 8
    unsigned short* ha = h0;
    unsigned short* hb = h1;
    for (int l = 0; l < LAYERS; l++) {
        gemm_mfma<<<(N_NODES + 63) / 64, 256, 0, stream>>>(ha, Wsw + (size_t)l * 65536, hb, N_NODES);
        agg_slice<<<agg_grid, 256, 0, stream>>>(hb, cnt, col_src, dinv, convb + (size_t)l * HIDDEN, ha);
    }

    pool2_kernel<<<N_GRAPHS, 256, 0, stream>>>(ha, gstart, outW, outb, out);
}

// Round 11
// 466.775 us; speedup vs baseline: 1.9430x; 1.9430x over previous
//
#include <hip/hip_runtime.h>

#define N_NODES 50000
#define N_EDGES 800000
#define N_GRAPHS 512
#define HIDDEN 256
#define NODE_FEAT 9
#define LAYERS 4
#define BUCKET 64   // max degree capacity (mean 16, max ~35 for uniform random)

typedef float floatx4 __attribute__((ext_vector_type(4)));
typedef short short8 __attribute__((ext_vector_type(8)));

__device__ __forceinline__ float bf2f(unsigned u) {
    unsigned v = u << 16;
    float f;
    __builtin_memcpy(&f, &v, 4);
    return f;
}
__device__ __forceinline__ unsigned short f2bf(float f) {
    unsigned v;
    __builtin_memcpy(&v, &f, 4);
    v += 0x7FFFu + ((v >> 16) & 1u);   // round-to-nearest-even
    return (unsigned short)(v >> 16);
}

// ---------------- one-pass bucketed CSR build ----------------
__global__ void fillb_kernel(const int* __restrict__ src, const int* __restrict__ dst,
                             int* __restrict__ cnt, int* __restrict__ col_src, int E) {
    int e = blockIdx.x * blockDim.x + threadIdx.x;
    if (e < E) {
        int d = dst[e];
        int pos = atomicAdd(&cnt[d], 1);
        if (pos < BUCKET) col_src[d * BUCKET + pos] = src[e];
    }
}

__global__ void dinv_kernel(const int* __restrict__ cnt, float* __restrict__ dinv, int N) {
    int i = blockIdx.x * blockDim.x + threadIdx.x;
    if (i < N) dinv[i] = rsqrtf((float)(cnt[i] + 1));   // +1 self loop
}

// ---------------- graph boundary search (batch is sorted) ----------------
__global__ void findstart_kernel(const int* __restrict__ batch, int* __restrict__ gstart) {
    int g = blockIdx.x * blockDim.x + threadIdx.x;
    if (g > N_GRAPHS) return;
    if (g == N_GRAPHS) { gstart[g] = N_NODES; return; }
    int lo = 0, hi = N_NODES;
    while (lo < hi) {
        int mid = (lo + hi) >> 1;
        if (batch[mid] < g) lo = mid + 1; else hi = mid;
    }
    gstart[g] = lo;
}

// ---------------- W pre-pack into MFMA B-fragment layout (bf16) ----------------
__global__ __launch_bounds__(256) void packW_kernel(const float* __restrict__ W,
                                                    unsigned short* __restrict__ Wsw) {
    int idx = blockIdx.x * 256 + threadIdx.x;   // 0..32767
    int lane = idx & 63;
    int ct   = (idx >> 6) & 15;
    int ks   = (idx >> 10) & 7;
    int l    = idx >> 13;
    int n = ct * 16 + (lane & 15);
    int kbase = ks * 32 + (lane >> 4) * 8;
    const float* Wl = W + (size_t)l * HIDDEN * HIDDEN;
    alignas(16) unsigned short tmp[8];
    #pragma unroll
    for (int j = 0; j < 8; j++)
        tmp[j] = f2bf(Wl[(size_t)(kbase + j) * HIDDEN + n]);
    *(uint4*)&Wsw[(size_t)idx * 8] = *(const uint4*)tmp;
}

// ---------------- embed: h = relu(x @ embW + embb), bf16 out ----------------
__global__ __launch_bounds__(256) void embed_kernel(const float* __restrict__ x,
                                                    const float* __restrict__ W,
                                                    const float* __restrict__ b,
                                                    unsigned short* __restrict__ h) {
    int n = blockIdx.x;
    int c = threadIdx.x;
    float acc = b[c];
    #pragma unroll
    for (int k = 0; k < NODE_FEAT; k++)
        acc += x[n * NODE_FEAT + k] * W[k * HIDDEN + c];
    h[(size_t)n * HIDDEN + c] = f2bf(fmaxf(acc, 0.0f));
}

// ---------------- hw = h @ W  (bf16 MFMA; DMA staging + XOR-swizzled LDS) ----------------
// A-tile staged with global_load_lds width=16 into UNPADDED As[64][256].
// Swizzle: LDS physical 16B-chunk p of row r holds logical chunk p ^ (r&7),
// so the 16-row-strided ds_read_b128 in the K-loop is ~2-way (free) not 16-way.
__global__ __launch_bounds__(256) void gemm_mfma(const unsigned short* __restrict__ hin,
                                                 const unsigned short* __restrict__ Wsw,
                                                 unsigned short* __restrict__ hwout, int N) {
    __shared__ unsigned short As[64][256];   // 32 KB; reused as C-buffer in epilogue
    int t = threadIdx.x;
    int wv = t >> 6, lane = t & 63, quad = lane >> 4, l15 = lane & 15;
    int n0 = blockIdx.x * 64;

    // async DMA staging: wave wv stages segments wv*8..wv*8+7 (1 KB each = 2 rows)
    #pragma unroll
    for (int i = 0; i < 8; i++) {
        int seg = wv * 8 + i;
        int r = seg * 2 + (lane >> 5);          // per-lane row
        int n = n0 + r; if (n >= N) n = N - 1;  // clamp: garbage rows guarded at store
        int lchunk = (lane & 31) ^ (r & 7);     // logical chunk for this lane's slot
        const unsigned short* gp = hin + (size_t)n * HIDDEN + lchunk * 8;
        unsigned short* lp = &As[seg * 2][0];   // wave-uniform base; lane's 16B -> +lane*16
        __builtin_amdgcn_global_load_lds((const __attribute__((address_space(1))) void*)gp,
                                         (__attribute__((address_space(3))) void*)lp,
                                         16, 0, 0);
    }
    // prime 2-deep W-fragment prefetch (rotating 3-buffer)
    const short8* Wl = (const short8*)Wsw;
    short8 bq[3][4];
    #pragma unroll
    for (int p = 0; p < 2; p++)
        #pragma unroll
        for (int ci = 0; ci < 4; ci++)
            bq[p][ci] = Wl[(size_t)(p * 16 + wv * 4 + ci) * 64 + lane];
    __syncthreads();   // drains the LDS-DMA (vmcnt) per barrier semantics

    floatx4 acc[4][4];
    #pragma unroll
    for (int i = 0; i < 4; i++)
        #pragma unroll
        for (int j = 0; j < 4; j++)
            acc[i][j] = (floatx4){0.f, 0.f, 0.f, 0.f};

    #pragma unroll
    for (int ks = 0; ks < 8; ks++) {
        if (ks < 6) {
            #pragma unroll
            for (int ci = 0; ci < 4; ci++)
                bq[(ks + 2) % 3][ci] = Wl[(size_t)((ks + 2) * 16 + wv * 4 + ci) * 64 + lane];
        }
        short8 a[4];
        #pragma unroll
        for (int rt = 0; rt < 4; rt++)
            a[rt] = *(const short8*)&As[rt * 16 + l15][(((ks * 4 + quad) ^ (l15 & 7)) * 8)];
        #pragma unroll
        for (int rt = 0; rt < 4; rt++)
            #pragma unroll
            for (int ci = 0; ci < 4; ci++)
                acc[rt][ci] = __builtin_amdgcn_mfma_f32_16x16x32_bf16(a[rt], bq[ks % 3][ci], acc[rt][ci], 0, 0, 0);
    }

    // epilogue: transpose via LDS (reuse As, no swizzle: self-consistent write/read)
    __syncthreads();   // all K-loop ds_reads done
    #pragma unroll
    for (int rt = 0; rt < 4; rt++) {
        #pragma unroll
        for (int ci = 0; ci < 4; ci++) {
            int col = (wv * 4 + ci) * 16 + l15;
            int rowb = rt * 16 + quad * 4;
            #pragma unroll
            for (int reg = 0; reg < 4; reg++)
                As[rowb + reg][col] = f2bf(acc[rt][ci][reg]);
        }
    }
    __syncthreads();
    #pragma unroll
    for (int i = 0; i < 8; i++) {
        int j = t + i * 256;
        int r = j >> 5;
        int c = j & 31;
        int n = n0 + r;
        if (n < N)
            *(uint4*)&hwout[(size_t)n * HIDDEN + c * 8] = *(const uint4*)&As[r][c * 8];
    }
}

// ---------------- aggregation: wave-per-node, 4 cols/lane (8B gathers) ----------------
__global__ __launch_bounds__(256) void agg_kernel(const unsigned short* __restrict__ hw,
                                                  const int* __restrict__ cnt,
                                                  const int* __restrict__ col_src,
                                                  const float* __restrict__ dinv,
                                                  const float* __restrict__ bias,
                                                  unsigned short* __restrict__ hout) {
    __shared__ uint2 sEdge[4][64];
    int wv = threadIdx.x >> 6, lane = threadIdx.x & 63;
    int n = blockIdx.x * 4 + wv;
    if (n >= N_NODES) return;
    float dn = dinv[n];
    int deg = cnt[n]; if (deg > BUCKET) deg = BUCKET;

    uint2 s2 = ((const uint2*)(hw + (size_t)n * HIDDEN))[lane];
    float4 b4 = *(const float4*)&bias[4 * lane];
    float selfc = dn * dn;
    float a0 = bf2f(s2.x & 0xFFFFu) * selfc + b4.x;
    float a1 = bf2f(s2.x >> 16)     * selfc + b4.y;
    float a2 = bf2f(s2.y & 0xFFFFu) * selfc + b4.z;
    float a3 = bf2f(s2.y >> 16)     * selfc + b4.w;

    if (lane < deg) {
        int s = col_src[n * BUCKET + lane];
        float nr = dinv[s] * dn;
        unsigned nrb;
        __builtin_memcpy(&nrb, &nr, 4);
        sEdge[wv][lane] = make_uint2((unsigned)s, nrb);
    }
    // same-wave LDS write->read: ordered by lgkmcnt, no barrier needed
    for (int i = 0; i < deg; i++) {
        uint2 p = sEdge[wv][i];
        float nr;
        __builtin_memcpy(&nr, &p.y, 4);
        uint2 u = ((const uint2*)(hw + (size_t)p.x * HIDDEN))[lane];
        a0 += nr * bf2f(u.x & 0xFFFFu);
        a1 += nr * bf2f(u.x >> 16);
        a2 += nr * bf2f(u.y & 0xFFFFu);
        a3 += nr * bf2f(u.y >> 16);
    }
    unsigned p0 = (unsigned)f2bf(fmaxf(a0, 0.0f)) | ((unsigned)f2bf(fmaxf(a1, 0.0f)) << 16);
    unsigned p1 = (unsigned)f2bf(fmaxf(a2, 0.0f)) | ((unsigned)f2bf(fmaxf(a3, 0.0f)) << 16);
    ((uint2*)(hout + (size_t)n * HIDDEN))[lane] = make_uint2(p0, p1);
}

// ---------------- pool + head, no atomics ----------------
__global__ __launch_bounds__(256) void pool2_kernel(const unsigned short* __restrict__ h,
                                                    const int* __restrict__ gstart,
                                                    const float* __restrict__ outW,
                                                    const float* __restrict__ outb,
                                                    float* __restrict__ out) {
    __shared__ float sred[4];
    int g = blockIdx.x;
    int t = threadIdx.x;
    int s = gstart[g], e = gstart[g + 1];
    int half = t >> 7;
    int tc = t & 127;
    float w0 = outW[2 * tc], w1 = outW[2 * tc + 1];
    float acc = 0.0f;
    for (int n = s + half; n < e; n += 2) {
        unsigned u = *(const unsigned*)&h[(size_t)n * HIDDEN + 2 * tc];
        acc += w0 * bf2f(u & 0xFFFFu) + w1 * bf2f(u >> 16);
    }
    #pragma unroll
    for (int off = 32; off > 0; off >>= 1) acc += __shfl_down(acc, off, 64);
    if ((t & 63) == 0) sred[t >> 6] = acc;
    __syncthreads();
    if (t == 0) {
        float tot = sred[0] + sred[1] + sred[2] + sred[3];
        float cntf = (float)(e - s);
        out[g] = tot / fmaxf(cntf, 1.0f) + outb[0];
    }
}

extern "C" void kernel_launch(void* const* d_in, const int* in_sizes, int n_in,
                              void* d_out, int out_size, void* d_ws, size_t ws_size,
                              hipStream_t stream) {
    const float* x     = (const float*)d_in[0];
    const int*   edge  = (const int*)d_in[1];
    const int*   src   = edge;
    const int*   dst   = edge + N_EDGES;
    const int*   batch = (const int*)d_in[2];
    const float* embW  = (const float*)d_in[3];
    const float* embb  = (const float*)d_in[4];
    const float* convW = (const float*)d_in[5];
    const float* convb = (const float*)d_in[6];
    const float* outW  = (const float*)d_in[7];
    const float* outb  = (const float*)d_in[8];
    float* out = (float*)d_out;

    char* ws = (char*)d_ws;
    size_t off = 0;
    auto take = [&](size_t bytes) { char* p = ws + off; off += (bytes + 255) & ~(size_t)255; return p; };
    int*   cnt     = (int*)  take((size_t)N_NODES * 4);
    int*   col_src = (int*)  take((size_t)N_NODES * BUCKET * 4);
    float* dinv    = (float*)take((size_t)N_NODES * 4);
    int*   gstart  = (int*)  take((size_t)(N_GRAPHS + 1) * 4);
    unsigned short* Wsw = (unsigned short*)take((size_t)LAYERS * 8 * 16 * 64 * 8 * 2);
    unsigned short* h0  = (unsigned short*)take((size_t)N_NODES * HIDDEN * 2);
    unsigned short* h1  = (unsigned short*)take((size_t)N_NODES * HIDDEN * 2);

    hipMemsetAsync(cnt, 0, (size_t)N_NODES * 4, stream);

    fillb_kernel<<<(N_EDGES + 255) / 256, 256, 0, stream>>>(src, dst, cnt, col_src, N_EDGES);
    dinv_kernel<<<(N_NODES + 255) / 256, 256, 0, stream>>>(cnt, dinv, N_NODES);
    findstart_kernel<<<3, 256, 0, stream>>>(batch, gstart);
    packW_kernel<<<128, 256, 0, stream>>>(convW, Wsw);
    embed_kernel<<<N_NODES, 256, 0, stream>>>(x, embW, embb, h0);

    unsigned short* ha = h0;
    unsigned short* hb = h1;
    for (int l = 0; l < LAYERS; l++) {
        gemm_mfma<<<(N_NODES + 63) / 64, 256, 0, stream>>>(ha, Wsw + (size_t)l * 65536, hb, N_NODES);
        agg_kernel<<<(N_NODES + 3) / 4, 256, 0, stream>>>(hb, cnt, col_src, dinv, convb + (size_t)l * HIDDEN, ha);
    }

    pool2_kernel<<<N_GRAPHS, 256, 0, stream>>>(ha, gstart, outW, outb, out);
}